// Round 3
// baseline (214.485 us; speedup 1.0000x reference)
//
#include <hip/hip_runtime.h>
#include <hip/hip_bf16.h>

#define NROWS 131072
#define KEXP 16
#define MPC 128
#define DIMD 64

typedef float f32x4 __attribute__((ext_vector_type(4)));
typedef short s16x8 __attribute__((ext_vector_type(8)));

#define L2E 1.4426950408889634f
#define LN2 0.6931471805599453f

static __device__ inline unsigned int b2u(__hip_bfloat162 h) {
    union { __hip_bfloat162 h; unsigned int u; } c;
    c.h = h;
    return c.u;
}

// pack 8 fp32 (scaled) into 8 bf16 in an int4
static __device__ inline int4 cvt8(float4 f0, float4 f1, float sc) {
    __hip_bfloat162 p0 = __float22bfloat162_rn(make_float2(f0.x * sc, f0.y * sc));
    __hip_bfloat162 p1 = __float22bfloat162_rn(make_float2(f0.z * sc, f0.w * sc));
    __hip_bfloat162 p2 = __float22bfloat162_rn(make_float2(f1.x * sc, f1.y * sc));
    __hip_bfloat162 p3 = __float22bfloat162_rn(make_float2(f1.z * sc, f1.w * sc));
    int4 pk;
    pk.x = (int)b2u(p0); pk.y = (int)b2u(p1); pk.z = (int)b2u(p2); pk.w = (int)b2u(p3);
    return pk;
}

// Single fused kernel. Block = 256 threads (4 waves) owns 128 rows.
// Stage x once as bf16 fragments in LDS (1 barrier). Wave w loops experts
// k = e*4+w, e=0..3: load B from fp32 `a` (L2-resident, 512 KB) with in-register
// *log2e + bf16 convert; eb = exp(b) inline. Weighted lse accumulated across
// experts in registers; one barrier; direct coalesced store of final out.
// No prep kernel, no combine kernel, no workspace, no atomics.
__global__ __launch_bounds__(256, 3)
void fused_kernel(const float* __restrict__ x, const float* __restrict__ s,
                  const float* __restrict__ a, const float* __restrict__ b,
                  float* __restrict__ out) {
    __shared__ int4 xbuf[1024];          // 16 KB: [g(8)][dc(2)][l(64)] 16B frags
    __shared__ float partial[4][128];    // per-wave row results

    const int tid  = threadIdx.x;
    const int w    = tid >> 6;
    const int l    = tid & 63;
    const int li   = l & 15;
    const int quad = l >> 4;

    const int r_base = blockIdx.x * 128;

    // stage 128 rows of x into LDS in MFMA A-fragment order (4 entries/thread)
#pragma unroll
    for (int i = 0; i < 4; ++i) {
        const int e   = i * 256 + tid;
        const int g   = e >> 7;
        const int dc  = (e >> 6) & 1;
        const int ll  = e & 63;
        const int sli = ll & 15;
        const int sq  = ll >> 4;
        const float* gp = x + (r_base + g * 16 + sli) * DIMD + dc * 32 + sq * 8;
        float4 f0 = *(const float4*)(gp);
        float4 f1 = *(const float4*)(gp + 4);
        xbuf[e] = cvt8(f0, f1, 1.0f);
    }
    __syncthreads();

    float racc[8];
#pragma unroll
    for (int g = 0; g < 8; ++g) racc[g] = 0.f;

    for (int e = 0; e < 4; ++e) {
        const int k = e * 4 + w;

        // B fragments from fp32 a, scaled by log2e: lane holds m=t*16+li, d=dc*32+quad*8..+7
        union { int4 i; s16x8 v; } Bf[16];
#pragma unroll
        for (int t = 0; t < 8; ++t) {
            const float* p = a + ((size_t)(k * MPC + t * 16 + li) * DIMD + quad * 8);
            float4 f00 = *(const float4*)(p);
            float4 f01 = *(const float4*)(p + 4);
            float4 f10 = *(const float4*)(p + 32);
            float4 f11 = *(const float4*)(p + 36);
            Bf[t * 2 + 0].i = cvt8(f00, f01, L2E);
            Bf[t * 2 + 1].i = cvt8(f10, f11, L2E);
        }
        float eb[8];
#pragma unroll
        for (int t = 0; t < 8; ++t) eb[t] = __expf(b[k * MPC + t * 16 + li]);
        const float sk2 = s[k] * LN2;

        for (int g = 0; g < 8; ++g) {
            const short* xsp = (const short*)xbuf + g * 1024;
            s16x8 a0 = *(const s16x8*)(xsp + l * 8);
            s16x8 a1 = *(const s16x8*)(xsp + 512 + l * 8);

            f32x4 acc[8];
#pragma unroll
            for (int t = 0; t < 8; ++t) {
                f32x4 z = {0.f, 0.f, 0.f, 0.f};
                acc[t] = __builtin_amdgcn_mfma_f32_16x16x32_bf16(a0, Bf[t * 2 + 0].v, z, 0, 0, 0);
                acc[t] = __builtin_amdgcn_mfma_f32_16x16x32_bf16(a1, Bf[t * 2 + 1].v, acc[t], 0, 0, 0);
            }

            // lse in log2 domain; butterfly over li leaves sums on all 16 lanes
            float sums[4];
#pragma unroll
            for (int j = 0; j < 4; ++j) {
                float sum = 0.f;
#pragma unroll
                for (int t = 0; t < 8; ++t)
                    sum = fmaf(eb[t], __builtin_amdgcn_exp2f(acc[t][j]), sum);
                sum += __shfl_xor(sum, 1);
                sum += __shfl_xor(sum, 2);
                sum += __shfl_xor(sum, 4);
                sum += __shfl_xor(sum, 8);
                sums[j] = sum;
            }
            const int m3 = li & 3;
            float v = sums[0];
            v = (m3 == 1) ? sums[1] : v;
            v = (m3 == 2) ? sums[2] : v;
            v = (m3 == 3) ? sums[3] : v;
            racc[g] += sk2 * __log2f(v);
        }
    }

#pragma unroll
    for (int g = 0; g < 8; ++g)
        if (li < 4) partial[w][g * 16 + quad * 4 + li] = racc[g];
    __syncthreads();

    if (tid < 128) {
        out[r_base + tid] =
            partial[0][tid] + partial[1][tid] + partial[2][tid] + partial[3][tid];
    }
}

extern "C" void kernel_launch(void* const* d_in, const int* in_sizes, int n_in,
                              void* d_out, int out_size, void* d_ws, size_t ws_size,
                              hipStream_t stream) {
    const float* x = (const float*)d_in[0];
    const float* s = (const float*)d_in[1];
    const float* a = (const float*)d_in[2];
    const float* b = (const float*)d_in[3];
    float* out = (float*)d_out;

    fused_kernel<<<NROWS / 128, 256, 0, stream>>>(x, s, a, b, out);
}

// Round 4
// 137.750 us; speedup vs baseline: 1.5571x; 1.5571x over previous
//
#include <hip/hip_runtime.h>
#include <hip/hip_bf16.h>

#define NROWS 131072
#define KEXP 16
#define MPC 128
#define DIMD 64

typedef float f32x4 __attribute__((ext_vector_type(4)));
typedef short s16x8 __attribute__((ext_vector_type(8)));

#define L2E 1.4426950408889634f
#define LN2 0.6931471805599453f

// 16-lane reduction network entirely in DPP (no LDS pipe):
// xor1 = quad_perm(1,0,3,2)=0xB1, xor2 = quad_perm(2,3,0,1)=0x4E,
// xor7 = row_half_mirror=0x141, xor15 = row_mirror=0x140
#define DPP_ADD(v, ctrl) \
    ((v) + __int_as_float(__builtin_amdgcn_update_dpp( \
         0, __float_as_int(v), (ctrl), 0xF, 0xF, true)))

static __device__ inline unsigned int b2u(__hip_bfloat162 h) {
    union { __hip_bfloat162 h; unsigned int u; } c;
    c.h = h;
    return c.u;
}

// pack 8 fp32 into 8 bf16 (no scale)
static __device__ inline int4 cvt8(float4 f0, float4 f1) {
    __hip_bfloat162 p0 = __float22bfloat162_rn(make_float2(f0.x, f0.y));
    __hip_bfloat162 p1 = __float22bfloat162_rn(make_float2(f0.z, f0.w));
    __hip_bfloat162 p2 = __float22bfloat162_rn(make_float2(f1.x, f1.y));
    __hip_bfloat162 p3 = __float22bfloat162_rn(make_float2(f1.z, f1.w));
    int4 pk;
    pk.x = (int)b2u(p0); pk.y = (int)b2u(p1); pk.z = (int)b2u(p2); pk.w = (int)b2u(p3);
    return pk;
}

// prep: abf = bf16(a * log2e)  (256 KB, stays L2-resident for the main kernel)
__global__ void prep_kernel(const float* __restrict__ a, short* __restrict__ abf) {
    int i = (blockIdx.x * 256 + threadIdx.x) * 4;
    float4 v = *(const float4*)(a + i);
    __hip_bfloat162 p0 = __float22bfloat162_rn(make_float2(v.x * L2E, v.y * L2E));
    __hip_bfloat162 p1 = __float22bfloat162_rn(make_float2(v.z * L2E, v.w * L2E));
    uint2 u;
    u.x = b2u(p0);
    u.y = b2u(p1);
    *(uint2*)(abf + i) = u;
}

// Block = 512 threads (8 waves) owns 128 rows and ALL 16 experts.
// 32 (expert, m-half) tasks; wave w does tasks tt*8+w, tt=0..3. Per task:
// Bf = 8 s16x8 (32 VGPR) from L2-hot abf, bias b*log2e folded into MFMA C-init.
// g-loop over 8 row-groups: 2 ds_read_b128 + 8 MFMA + 16 exp2 + DPP reduction.
// Half-sums -> LDS (pad 17, conflict-free); one barrier; combine + log + store.
__global__ __launch_bounds__(512, 4)
void fused_kernel(const float* __restrict__ x, const float* __restrict__ s,
                  const short* __restrict__ abf, const float* __restrict__ b,
                  float* __restrict__ out) {
    __shared__ int4  xbuf[1024];          // 16 KB: [g(8)][dc(2)][l(64)] frags
    __shared__ float hs[2][128][17];      // 17.4 KB half-sums, padded
    __shared__ float partial[4][128];     // 2 KB

    const int tid  = threadIdx.x;
    const int w    = tid >> 6;
    const int l    = tid & 63;
    const int li   = l & 15;
    const int quad = l >> 4;

    const int r_base = blockIdx.x * 128;

    // stage 128 rows of x into LDS in MFMA A-fragment order (2 entries/thread)
#pragma unroll
    for (int i = 0; i < 2; ++i) {
        const int e   = i * 512 + tid;
        const int g   = e >> 7;
        const int dc  = (e >> 6) & 1;
        const int ll  = e & 63;
        const int sli = ll & 15;
        const int sq  = ll >> 4;
        const float* gp = x + (r_base + g * 16 + sli) * DIMD + dc * 32 + sq * 8;
        float4 f0 = *(const float4*)(gp);
        float4 f1 = *(const float4*)(gp + 4);
        xbuf[e] = cvt8(f0, f1);
    }
    __syncthreads();

    for (int tt = 0; tt < 4; ++tt) {
        const int id = tt * 8 + w;   // 0..31
        const int k  = id & 15;      // expert
        const int h  = id >> 4;      // m-half

        // B fragments for m in [h*64, h*64+64): lane holds m=h*64+t*16+li,
        // d = dc*32 + quad*8 .. +7   (32 VGPRs)
        s16x8 Bf[8];
#pragma unroll
        for (int t = 0; t < 4; ++t) {
            const short* p = abf + ((k * MPC + h * 64 + t * 16 + li) * DIMD + quad * 8);
            Bf[t * 2 + 0] = *(const s16x8*)(p);
            Bf[t * 2 + 1] = *(const s16x8*)(p + 32);
        }
        // bias in log2 domain, folded into MFMA C operand (depends on col=m only)
        float lb[4];
#pragma unroll
        for (int t = 0; t < 4; ++t)
            lb[t] = b[k * MPC + h * 64 + t * 16 + li] * L2E;

        for (int g = 0; g < 8; ++g) {
            const short* xsp = (const short*)xbuf + g * 1024;
            s16x8 a0 = *(const s16x8*)(xsp + l * 8);
            s16x8 a1 = *(const s16x8*)(xsp + 512 + l * 8);

            f32x4 acc[4];
#pragma unroll
            for (int t = 0; t < 4; ++t) {
                f32x4 c = {lb[t], lb[t], lb[t], lb[t]};
                acc[t] = __builtin_amdgcn_mfma_f32_16x16x32_bf16(a0, Bf[t * 2 + 0], c, 0, 0, 0);
                acc[t] = __builtin_amdgcn_mfma_f32_16x16x32_bf16(a1, Bf[t * 2 + 1], acc[t], 0, 0, 0);
            }

            // sum over this half's 64 m: 4 in-lane exp2 + full 16-lane DPP network
            float sums[4];
#pragma unroll
            for (int j = 0; j < 4; ++j) {
                float s01 = __builtin_amdgcn_exp2f(acc[0][j]) + __builtin_amdgcn_exp2f(acc[1][j]);
                float s23 = __builtin_amdgcn_exp2f(acc[2][j]) + __builtin_amdgcn_exp2f(acc[3][j]);
                float sum = s01 + s23;
                sum = DPP_ADD(sum, 0xB1);   // xor1
                sum = DPP_ADD(sum, 0x4E);   // xor2
                sum = DPP_ADD(sum, 0x141);  // xor7 (row_half_mirror)
                sum = DPP_ADD(sum, 0x140);  // xor15 (row_mirror)
                sums[j] = sum;
            }
            const int m3 = li & 3;
            float v = sums[0];
            v = (m3 == 1) ? sums[1] : v;
            v = (m3 == 2) ? sums[2] : v;
            v = (m3 == 3) ? sums[3] : v;
            if (li < 4) hs[h][g * 16 + quad * 4 + li][k] = v;
        }
    }
    __syncthreads();

    // combine halves, take log, weight by s[k], reduce over experts
    {
        const int r    = tid & 127;
        const int ksub = tid >> 7;   // 0..3, wave-uniform
        float acc2 = 0.f;
#pragma unroll
        for (int e = 0; e < 4; ++e) {
            const int k = ksub * 4 + e;
            float tot = hs[0][r][k] + hs[1][r][k];
            acc2 = fmaf(s[k] * LN2, __log2f(tot), acc2);
        }
        partial[ksub][r] = acc2;
    }
    __syncthreads();

    if (tid < 128) {
        out[r_base + tid] =
            partial[0][tid] + partial[1][tid] + partial[2][tid] + partial[3][tid];
    }
}

extern "C" void kernel_launch(void* const* d_in, const int* in_sizes, int n_in,
                              void* d_out, int out_size, void* d_ws, size_t ws_size,
                              hipStream_t stream) {
    const float* x = (const float*)d_in[0];
    const float* s = (const float*)d_in[1];
    const float* a = (const float*)d_in[2];
    const float* b = (const float*)d_in[3];
    float* out = (float*)d_out;

    short* abf = (short*)d_ws;  // 256 KB

    prep_kernel<<<(KEXP * MPC * DIMD) / 1024, 256, 0, stream>>>(a, abf);
    fused_kernel<<<NROWS / 128, 512, 0, stream>>>(x, s, abf, b, out);
}

// Round 5
// 135.125 us; speedup vs baseline: 1.5873x; 1.0194x over previous
//
#include <hip/hip_runtime.h>
#include <hip/hip_bf16.h>

#define NROWS 131072
#define KEXP 16
#define MPC 128
#define DIMD 64

typedef float f32x4  __attribute__((ext_vector_type(4)));
typedef float f32x16 __attribute__((ext_vector_type(16)));
typedef short s16x8  __attribute__((ext_vector_type(8)));

#define L2E 1.4426950408889634f
#define LN2 0.6931471805599453f

static __device__ inline unsigned int b2u(__hip_bfloat162 h) {
    union { __hip_bfloat162 h; unsigned int u; } c;
    c.h = h;
    return c.u;
}

// pack 8 fp32 (scaled) -> 8 bf16 in an int4
static __device__ inline int4 cvt8s(float4 f0, float4 f1, float sc) {
    __hip_bfloat162 p0 = __float22bfloat162_rn(make_float2(f0.x * sc, f0.y * sc));
    __hip_bfloat162 p1 = __float22bfloat162_rn(make_float2(f0.z * sc, f0.w * sc));
    __hip_bfloat162 p2 = __float22bfloat162_rn(make_float2(f1.x * sc, f1.y * sc));
    __hip_bfloat162 p3 = __float22bfloat162_rn(make_float2(f1.z * sc, f1.w * sc));
    int4 pk;
    pk.x = (int)b2u(p0); pk.y = (int)b2u(p1); pk.z = (int)b2u(p2); pk.w = (int)b2u(p3);
    return pk;
}

// Transposed-MFMA fused kernel. Block = 256 threads (4 waves); wave owns 64 rows.
// MFMA 32x32x16: A = a-tile (m on rows), B = x-frags (n on cols, 32 VGPR,
// persistent across all 16 experts). C/D: col n = lane&31,
// row m = (reg&3) + 8*(reg>>2) + 4*(lane>>5)  [m74/m101 verified].
// A layout: m = lane&31, k = (lane>>5)*8+e ; B: n = lane&31, k = (lane>>5)*8+e.
// Per expert: A (bf16, x log2e) double-buffered in LDS; bias b*log2e folded into
// the MFMA C-init via broadcast ds_read_b128 from an all-expert lb table.
// Softmax sum over m is in-lane (16 regs/mtile) + ONE shfl_xor(32) per expert.
__global__ __launch_bounds__(256, 2)
void fused_kernel(const float* __restrict__ x, const float* __restrict__ s,
                  const float* __restrict__ a, const float* __restrict__ b,
                  float* __restrict__ out) {
    __shared__ int4  abuf[2][1024];     // 32 KB: A[k] frags: [mt(4)][c(4)][lane(64)]
    __shared__ float lb[KEXP * MPC];    // 8 KB: b * log2e, all experts

    const int tid  = threadIdx.x;
    const int w    = tid >> 6;
    const int l    = tid & 63;
    const int ln   = l & 31;
    const int half = l >> 5;

    const int r0 = blockIdx.x * 256 + w * 64;

    // ---- stage lb (all experts) ----
    {
        const float* bp = b + tid * 8;
        float4 b0 = *(const float4*)(bp);
        float4 b1 = *(const float4*)(bp + 4);
        float4 o0 = {b0.x * L2E, b0.y * L2E, b0.z * L2E, b0.w * L2E};
        float4 o1 = {b1.x * L2E, b1.y * L2E, b1.z * L2E, b1.w * L2E};
        *(float4*)(lb + tid * 8)     = o0;
        *(float4*)(lb + tid * 8 + 4) = o1;
    }

    // ---- x B-fragments, persistent: Bf[nt][c] = x[r0+nt*32+ln][c*16+half*8 ..+7] ----
    union { int4 i; s16x8 v; } Bf[2][4];
#pragma unroll
    for (int nt = 0; nt < 2; ++nt)
#pragma unroll
        for (int c = 0; c < 4; ++c) {
            const float* gp = x + (size_t)(r0 + nt * 32 + ln) * DIMD + c * 16 + half * 8;
            float4 f0 = *(const float4*)(gp);
            float4 f1 = *(const float4*)(gp + 4);
            Bf[nt][c].i = cvt8s(f0, f1, 1.0f);
        }

    // ---- stage A[0] into abuf[0]: unit u = fb*64 + ul; fb = mt*4+c;
    //      value = a[0][ (fb>>2)*32 + (ul&31) ][ (fb&3)*16 + (ul>>5)*8 ..+7 ] * log2e
#pragma unroll
    for (int i = 0; i < 4; ++i) {
        const int u  = i * 256 + tid;
        const int fb = u >> 6;
        const int ul = u & 63;
        const float* p = a + (size_t)((fb >> 2) * 32 + (ul & 31)) * DIMD
                           + (fb & 3) * 16 + (ul >> 5) * 8;
        float4 f0 = *(const float4*)(p);
        float4 f1 = *(const float4*)(p + 4);
        abuf[0][u] = cvt8s(f0, f1, L2E);
    }
    __syncthreads();

    float racc0 = 0.f, racc1 = 0.f;

    for (int k = 0; k < KEXP; ++k) {
        // prefetch next expert's fp32 A early (lands under compute)
        float4 ga[8];
        if (k + 1 < KEXP) {
            const float* ap = a + (size_t)(k + 1) * MPC * DIMD;
#pragma unroll
            for (int i = 0; i < 4; ++i) {
                const int u  = i * 256 + tid;
                const int fb = u >> 6;
                const int ul = u & 63;
                const float* p = ap + (size_t)((fb >> 2) * 32 + (ul & 31)) * DIMD
                                    + (fb & 3) * 16 + (ul >> 5) * 8;
                ga[i * 2]     = *(const float4*)(p);
                ga[i * 2 + 1] = *(const float4*)(p + 4);
            }
        }

        const int   kb  = k & 1;
        const float sk2 = s[k] * LN2;
        float esum0 = 0.f, esum1 = 0.f;

#pragma unroll
        for (int mt = 0; mt < 4; ++mt) {
            // bias C-init: rows (reg&3)+8*(reg>>2)+4*half + 32*mt  (broadcast reads)
            f32x4 lbv[4];
#pragma unroll
            for (int g = 0; g < 4; ++g)
                lbv[g] = *(const f32x4*)(lb + k * MPC + mt * 32 + g * 8 + half * 4);

            // A-frags for this mtile (conflict-free: addr = l*16 within each 1KB frag)
            s16x8 Af[4];
#pragma unroll
            for (int c = 0; c < 4; ++c)
                Af[c] = *(const s16x8*)&abuf[kb][mt * 256 + c * 64 + l];

            f32x16 acc0, acc1;
#pragma unroll
            for (int g = 0; g < 4; ++g)
#pragma unroll
                for (int j = 0; j < 4; ++j) {
                    acc0[g * 4 + j] = lbv[g][j];
                    acc1[g * 4 + j] = lbv[g][j];
                }
#pragma unroll
            for (int c = 0; c < 4; ++c)
                acc0 = __builtin_amdgcn_mfma_f32_32x32x16_bf16(Af[c], Bf[0][c].v, acc0, 0, 0, 0);
#pragma unroll
            for (int c = 0; c < 4; ++c)
                acc1 = __builtin_amdgcn_mfma_f32_32x32x16_bf16(Af[c], Bf[1][c].v, acc1, 0, 0, 0);

            // in-lane sum over this mtile's 16 m-rows (tree)
            float e0 = 0.f, e1 = 0.f;
            {
                float t0[8], t1[8];
#pragma unroll
                for (int r = 0; r < 8; ++r) {
                    t0[r] = __builtin_amdgcn_exp2f(acc0[2 * r]) + __builtin_amdgcn_exp2f(acc0[2 * r + 1]);
                    t1[r] = __builtin_amdgcn_exp2f(acc1[2 * r]) + __builtin_amdgcn_exp2f(acc1[2 * r + 1]);
                }
#pragma unroll
                for (int r = 0; r < 4; ++r) { t0[r] += t0[r + 4]; t1[r] += t1[r + 4]; }
                e0 = (t0[0] + t0[1]) + (t0[2] + t0[3]);
                e1 = (t1[0] + t1[1]) + (t1[2] + t1[3]);
            }
            esum0 += e0;
            esum1 += e1;
        }

        // one cross-lane step: combine the two k-halves (lanes l and l^32)
        float tot0 = esum0 + __shfl_xor(esum0, 32);
        float tot1 = esum1 + __shfl_xor(esum1, 32);
        racc0 = fmaf(sk2, __log2f(tot0), racc0);
        racc1 = fmaf(sk2, __log2f(tot1), racc1);

        // write staged A[k+1] into the other buffer
        if (k + 1 < KEXP) {
#pragma unroll
            for (int i = 0; i < 4; ++i)
                abuf[kb ^ 1][i * 256 + tid] = cvt8s(ga[i * 2], ga[i * 2 + 1], L2E);
        }
        __syncthreads();
    }

    // store: lane l -> row r0 + l  (half 0 = ntile0 rows, half 1 = ntile1 rows;
    // racc values are duplicated across halves after the xor32 combine)
    out[r0 + l] = half ? racc1 : racc0;
}

extern "C" void kernel_launch(void* const* d_in, const int* in_sizes, int n_in,
                              void* d_out, int out_size, void* d_ws, size_t ws_size,
                              hipStream_t stream) {
    const float* x = (const float*)d_in[0];
    const float* s = (const float*)d_in[1];
    const float* a = (const float*)d_in[2];
    const float* b = (const float*)d_in[3];
    float* out = (float*)d_out;

    fused_kernel<<<NROWS / 256, 256, 0, stream>>>(x, s, a, b, out);
}